// Round 2
// baseline (480.698 us; speedup 1.0000x reference)
//
#include <hip/hip_runtime.h>
#include <hip/hip_fp16.h>

#define N_ROWS 32768
#define KCODES 8192
#define CDIM   256
#define NSUB   (KCODES / 16)     // 512 subtiles of 16 codes
// dot-scale margin: covers bf16-dot err + fp16-RTZ storage (~3e-5) + e2 spread (<=1.9e-6).
// Certified need ~1.05e-4; previous passing config was equivalent to 2.0e-4 dot-scale.
#define MARGIN_DOT 2.2e-4f
#define LSTR   64                // LDS row stride in bf16 units (no pad; XOR swizzle instead)

typedef __attribute__((ext_vector_type(8))) short bf16x8;
typedef __attribute__((ext_vector_type(4))) float f32x4;
typedef __attribute__((ext_vector_type(2))) _Float16 h2_t;

// async global->LDS, 16B per lane; LDS dest is wave-uniform base + lane*16 (linear),
// so the XOR swizzle is applied to the per-lane GLOBAL source address instead (rule #21).
#define GLOAD_LDS16(g, l)                                                              \
    __builtin_amdgcn_global_load_lds((const __attribute__((address_space(1))) void*)(g), \
                                     (__attribute__((address_space(3))) void*)(l), 16, 0, 0)

__device__ __forceinline__ ushort f2bf_rne(float f) {
    unsigned u = __float_as_uint(f);
    u += 0x7fffu + ((u >> 16) & 1u);
    return (ushort)(u >> 16);
}

// one DPP max step on a packed half2 (row_shr pattern; result accumulates toward lane 15)
template <int CTRL>
__device__ __forceinline__ uint dpp_max_step(uint u) {
    uint s = (uint)__builtin_amdgcn_update_dpp((int)u, (int)u, CTRL, 0xf, 0xf, false);
    h2_t a = __builtin_bit_cast(h2_t, u);
    h2_t b = __builtin_bit_cast(h2_t, s);
    return __builtin_bit_cast(uint, __builtin_elementwise_max(a, b));
}

__device__ __forceinline__ uint row16_max(uint u) {
    u = dpp_max_step<0x111>(u);   // row_shr:1
    u = dpp_max_step<0x112>(u);   // row_shr:2
    u = dpp_max_step<0x114>(u);   // row_shr:4
    u = dpp_max_step<0x118>(u);   // row_shr:8  -> lane 15 of each 16-group holds max
    return u;
}

// ---------- phase 0: fused fp32->bf16 convert + row sum-of-squares for BOTH inputs ----------
__global__ void prep_kernel(const float* __restrict__ x, const float* __restrict__ wgt,
                            ushort* __restrict__ xb, ushort* __restrict__ wb,
                            float* __restrict__ t1, float* __restrict__ e2) {
    int wave = (blockIdx.x * blockDim.x + threadIdx.x) >> 6;
    int lane = threadIdx.x & 63;
    const float* src; ushort* bdst; float* sqdst; int row;
    if (wave < N_ROWS) { src = x; bdst = xb; sqdst = t1; row = wave; }
    else               { src = wgt; bdst = wb; sqdst = e2; row = wave - N_ROWS; }
    float4 v = *((const float4*)src + (size_t)row * (CDIM / 4) + lane);
    ushort4 o;
    o.x = f2bf_rne(v.x); o.y = f2bf_rne(v.y); o.z = f2bf_rne(v.z); o.w = f2bf_rne(v.w);
    *((ushort4*)bdst + (size_t)row * (CDIM / 4) + lane) = o;
    float s = v.x * v.x + v.y * v.y + v.z * v.z + v.w * v.w;
    for (int off = 32; off; off >>= 1) s += __shfl_down(s, off, 64);
    if (lane == 0) sqdst[row] = s;
}

// ---------- phase 1: 256x256 tile, 8 waves, double-buffered LDS, 2-phase pipeline ----------
// Waves 2x4: wave tile 128 rows x 64 codes. LDS = 2 bufs x (32KB X + 32KB W) = 128 KB.
// Score = raw dot (MAX per 16-code subtile); e2 folded into MARGIN_DOT (e2max = 3.8e-6).
// Pipeline: stage(c+1 -> buf^1) issued BEFORE compute(c); barrier (implicit vmcnt drain)
// once per chunk -> next chunk's loads fly under current chunk's ds_read+MFMA.
__launch_bounds__(512, 2)
__global__ void vq_mfma_kernel(const ushort* __restrict__ xb, const ushort* __restrict__ wb,
                               __half* __restrict__ minT) {
    __shared__ ushort lds[2][2][256 * LSTR];   // [buf][0=X,1=W] -> 128 KB exactly
    // mbT aliased onto buf0-X: first written after the final barrier (buf0 reads end at
    // cc=2's barrier; every wave passes cc=3's barrier before any mbT write). 16x264x2B.
    ushort (*mbT)[264] = (ushort (*)[264])&lds[0][0][0];

    const int t = threadIdx.x;
    const int w = t >> 6, lane = t & 63;
    const int ln15 = lane & 15, quad = lane >> 4;

    // XCD-contiguous remap (nwg=4096, 4096%8==0 -> simple bijection): each XCD owns a
    // contiguous bid range -> shared X row-panels and W col-panels stay in its L2.
    const int bid = (int)((blockIdx.x & 7) * (gridDim.x >> 3) + (blockIdx.x >> 3));
    const int rt = bid >> 5;            // 128 row tiles of 256 rows
    const int ct = bid & 31;            // 32 code tiles of 256 codes

    const int rbase = (w >> 2) * 128;   // wave row base (0 or 128)
    const int cbase = (w & 3) * 64;     // wave code base (0/64/128/192)

    // staging: per wave-call 8 rows x 64 cols (1KB); wave w owns rows [w*32, w*32+32)
    const int srow8  = lane >> 3;                    // row within 8-row group
    const int schunk = (lane & 7) ^ srow8;           // pre-swizzled source 16B chunk
    const ushort* xsrc = xb + (size_t)(rt * 256 + w * 32 + srow8) * CDIM + schunk * 8;
    const ushort* wsrc = wb + (size_t)(ct * 256 + w * 32 + srow8) * CDIM + schunk * 8;
    const int dofs = (w * 32) * LSTR;                // wave-uniform LDS dest offset

    f32x4 acc[8][4];
#pragma unroll
    for (int mi = 0; mi < 8; ++mi)
#pragma unroll
        for (int ni = 0; ni < 4; ++ni)
#pragma unroll
            for (int r = 0; r < 4; ++r) acc[mi][ni][r] = 0.f;

    // prologue: stage chunk 0 into buf 0
#pragma unroll
    for (int j = 0; j < 4; ++j) {
        GLOAD_LDS16(xsrc + (size_t)j * 8 * CDIM, &lds[0][0][dofs + j * 8 * LSTR]);
        GLOAD_LDS16(wsrc + (size_t)j * 8 * CDIM, &lds[0][1][dofs + j * 8 * LSTR]);
    }
    __syncthreads();

#pragma unroll
    for (int cc = 0; cc < 4; ++cc) {
        const int cur = cc & 1;
        if (cc < 3) {                                  // issue next-chunk loads FIRST
#pragma unroll
            for (int j = 0; j < 4; ++j) {
                GLOAD_LDS16(xsrc + (size_t)j * 8 * CDIM + (cc + 1) * 64,
                            &lds[cur ^ 1][0][dofs + j * 8 * LSTR]);
                GLOAD_LDS16(wsrc + (size_t)j * 8 * CDIM + (cc + 1) * 64,
                            &lds[cur ^ 1][1][dofs + j * 8 * LSTR]);
            }
        }
#pragma unroll
        for (int kk = 0; kk < 2; ++kk) {              // two k=32 MFMA steps per chunk
            const int swzA = (((kk * 4 + quad) ^ (ln15 & 7)) * 8);
            bf16x8 a[8], b[4];
#pragma unroll
            for (int mi = 0; mi < 8; ++mi)
                a[mi] = *(const bf16x8*)&lds[cur][0][(rbase + mi * 16 + ln15) * LSTR + swzA];
#pragma unroll
            for (int ni = 0; ni < 4; ++ni)
                b[ni] = *(const bf16x8*)&lds[cur][1][(cbase + ni * 16 + ln15) * LSTR + swzA];
#pragma unroll
            for (int mi = 0; mi < 8; ++mi)
#pragma unroll
                for (int ni = 0; ni < 4; ++ni)
                    acc[mi][ni] = __builtin_amdgcn_mfma_f32_16x16x32_bf16(a[mi], b[ni], acc[mi][ni], 0, 0, 0);
        }
        __syncthreads();                              // drains vmcnt -> next buf ready
    }

    // epilogue: per-subtile MAX of raw dot; packed-half DPP reduce (no e2, no negate)
#pragma unroll
    for (int mi = 0; mi < 8; ++mi)
#pragma unroll
        for (int ni = 0; ni < 4; ++ni) {
            uint u01 = __builtin_bit_cast(uint, __builtin_amdgcn_cvt_pkrtz(acc[mi][ni][0], acc[mi][ni][1]));
            uint u23 = __builtin_bit_cast(uint, __builtin_amdgcn_cvt_pkrtz(acc[mi][ni][2], acc[mi][ni][3]));
            u01 = row16_max(u01);
            u23 = row16_max(u23);
            if (ln15 == 15) {
                int rowb = rbase + mi * 16 + quad * 4;     // rows rowb..rowb+3 (C/D layout)
                int sb   = (cbase >> 4) + ni;              // 0..15
                *(uint*)&mbT[sb][rowb]     = u01;          // rows rowb, rowb+1
                *(uint*)&mbT[sb][rowb + 2] = u23;          // rows rowb+2, rowb+3
            }
        }
    __syncthreads();
    {
        // minT layout [rt][ct(32)][row(256)][sub(16)]: dense 8 KB per block, full lines.
        union { ushort s[8]; uint4 u; } r;
        const int row = t >> 1, hf = t & 1;
#pragma unroll
        for (int s = 0; s < 8; ++s) r.s[s] = mbT[hf * 8 + s][row];
        *(uint4*)(minT + ((((size_t)rt * 32 + ct) * 256 + row) * 2 + hf) * 8) = r.u;
    }
}

// ---------- phase 2: exact fp32 re-rank of candidate subtiles + fused gather ----------
__launch_bounds__(256, 4)
__global__ void vq_rerank_kernel(const float* __restrict__ x, const float* __restrict__ wgt,
                                 const float* __restrict__ t1, const float* __restrict__ e2,
                                 const __half* __restrict__ minT,
                                 float* __restrict__ out_q, float* __restrict__ out_i) {
    __shared__ float xrow[4][256];
    __shared__ int slist[4][40];
    const int t = threadIdx.x, w = t >> 6, lane = t & 63, quad = lane >> 4;
    const int row = blockIdx.x * 4 + w;

    // stage x row (1 KB) into LDS
    *(float4*)&xrow[w][lane * 4] = *((const float4*)(x + (size_t)row * CDIM) + lane);

    // read 512 subtile dot-maxima (8 per lane): lane l covers subtiles l*8..l*8+7
    // = [ct=l>>1][half=l&1] of minT's [rt][ct][row][16] layout.
    union { uint4 u; __half2 h2[4]; } raw;
    raw.u = ((const uint4*)minT)[((size_t)(row >> 8) * 32 + (lane >> 1)) * 512
                                 + (size_t)(row & 255) * 2 + (lane & 1)];
    float m[8];
#pragma unroll
    for (int i = 0; i < 4; ++i) {
        float2 f = __half22float2(raw.h2[i]);
        m[2 * i] = f.x;
        m[2 * i + 1] = f.y;
    }
    float lmax = m[0];
#pragma unroll
    for (int i = 1; i < 8; ++i) lmax = fmaxf(lmax, m[i]);
#pragma unroll
    for (int off = 1; off < 64; off <<= 1) lmax = fmaxf(lmax, __shfl_xor(lmax, off, 64));
    const float thresh = lmax - MARGIN_DOT;

    // build candidate subtile list (certified superset of exact-min codes)
    int base = 0;
#pragma unroll
    for (int s = 0; s < 8; ++s) {
        bool c = (m[s] >= thresh);
        unsigned long long mask = __ballot(c);
        if (c) {
            int pos = base + __popcll(mask & ((1ull << lane) - 1ull));
            if (pos < 40) slist[w][pos] = lane * 8 + s;
        }
        base += (int)__popcll(mask);
    }
    const int ncand = base < 40 ? base : 40;
    __syncthreads();

    const float t1r = t1[row];
    float best = 3.402823466e38f;
    int bestk = 0x7fffffff;
    for (int p = 0; p * 4 < ncand; ++p) {
        int li = p * 4 + quad;                 // 4 subtiles per pass, 16 lanes each
        float d = 3.402823466e38f;
        int k = 0x7fffffff;
        if (li < ncand) {
            int st = slist[w][li];
            k = st * 16 + (lane & 15);
            // EXACT accumulation order preserved: sequential c = 0..255 fmaf chain.
            // Double-buffered explicit register staging (8 float4 in flight) so load
            // latency hides under the previous chunk's 32 fmafs (VGPR 28 -> ~100:
            // round-1 compiler serialized the loads; this forces batching).
            const float4* wp = (const float4*)(wgt + (size_t)k * CDIM);
            float4 buf[2][8];                  // fully unrolled -> all indices static
#pragma unroll
            for (int i = 0; i < 8; ++i) buf[0][i] = wp[i];
            float acc = 0.f;
#pragma unroll
            for (int g = 0; g < 8; ++g) {
                if (g < 7) {
#pragma unroll
                    for (int i = 0; i < 8; ++i) buf[(g + 1) & 1][i] = wp[(g + 1) * 8 + i];
                }
#pragma unroll
                for (int i = 0; i < 8; ++i) {
                    float4 wv = buf[g & 1][i];
                    float4 xv = *(const float4*)&xrow[w][(g * 8 + i) * 4];
                    acc = fmaf(xv.x, wv.x, acc);
                    acc = fmaf(xv.y, wv.y, acc);
                    acc = fmaf(xv.z, wv.z, acc);
                    acc = fmaf(xv.w, wv.w, acc);
                }
            }
            d = (t1r + e2[k]) - 2.0f * acc;    // exact distance, same chain as before
        }
        if (d < best || (d == best && k < bestk)) { best = d; bestk = k; }
    }
    // wave-reduce (d, k) with first-index tie-break (np argmin semantics)
#pragma unroll
    for (int off = 1; off < 64; off <<= 1) {
        float od = __shfl_xor(best, off, 64);
        int ok = __shfl_xor(bestk, off, 64);
        if (od < best || (od == best && ok < bestk)) { best = od; bestk = ok; }
    }

    // fused gather + index write
    const float4* src = (const float4*)(wgt + (size_t)bestk * CDIM);
    ((float4*)(out_q + (size_t)row * CDIM))[lane] = src[lane];
    if (lane == 0) out_i[row] = (float)bestk;
}

extern "C" void kernel_launch(void* const* d_in, const int* in_sizes, int n_in,
                              void* d_out, int out_size, void* d_ws, size_t ws_size,
                              hipStream_t stream) {
    const float* x = (const float*)d_in[0];   // (8,4096,256) fp32
    const float* wgt = (const float*)d_in[1]; // (8192,256) fp32

    float* out_q = (float*)d_out;
    float* out_i = out_q + (size_t)N_ROWS * CDIM;

    // workspace carve (all 16B aligned): e2, t1, minT, xb, wb  -> ~52.3 MB
    char* p = (char*)d_ws;
    float* e2 = (float*)p;               p += (size_t)KCODES * 4;
    float* t1 = (float*)p;               p += (size_t)N_ROWS * 4;
    __half* minT = (__half*)p;           p += (size_t)N_ROWS * NSUB * 2;
    ushort* xb = (ushort*)p;             p += (size_t)N_ROWS * CDIM * 2;
    ushort* wb = (ushort*)p;             p += (size_t)KCODES * CDIM * 2;

    prep_kernel<<<(N_ROWS + KCODES) / 4, 256, 0, stream>>>(x, wgt, xb, wb, t1, e2);

    vq_mfma_kernel<<<(N_ROWS / 256) * (KCODES / 256), 512, 0, stream>>>(xb, wb, minT);
    vq_rerank_kernel<<<N_ROWS / 4, 256, 0, stream>>>(x, wgt, t1, e2, minT, out_q, out_i);
}

// Round 3
// 419.236 us; speedup vs baseline: 1.1466x; 1.1466x over previous
//
#include <hip/hip_runtime.h>
#include <hip/hip_fp16.h>

#define N_ROWS 32768
#define KCODES 8192
#define CDIM   256
#define NSUB   (KCODES / 16)     // 512 subtiles of 16 codes
// dot-scale margin: covers bf16-dot err + fp16-RTZ storage (~3e-5) + e2 spread (<=1.9e-6).
// Certified need ~1.05e-4; round-2 passed with this exact value + raw-dot-max semantics.
#define MARGIN_DOT 2.2e-4f

typedef __attribute__((ext_vector_type(8))) short bf16x8;
typedef __attribute__((ext_vector_type(4))) float f32x4;

// async global->LDS, 16B per lane; LDS dest is wave-uniform base + lane*16 (linear),
// so the XOR swizzle is applied to the per-lane GLOBAL source address instead (rule #21).
#define GLOAD_LDS16(g, l)                                                              \
    __builtin_amdgcn_global_load_lds((const __attribute__((address_space(1))) void*)(g), \
                                     (__attribute__((address_space(3))) void*)(l), 16, 0, 0)

__device__ __forceinline__ ushort f2bf_rne(float f) {
    unsigned u = __float_as_uint(f);
    u += 0x7fffu + ((u >> 16) & 1u);
    return (ushort)(u >> 16);
}

// ---------- phase 0: fused fp32->bf16 convert + row sum-of-squares for BOTH inputs ----------
__global__ void prep_kernel(const float* __restrict__ x, const float* __restrict__ wgt,
                            ushort* __restrict__ xb, ushort* __restrict__ wb,
                            float* __restrict__ t1, float* __restrict__ e2) {
    int wave = (blockIdx.x * blockDim.x + threadIdx.x) >> 6;
    int lane = threadIdx.x & 63;
    const float* src; ushort* bdst; float* sqdst; int row;
    if (wave < N_ROWS) { src = x; bdst = xb; sqdst = t1; row = wave; }
    else               { src = wgt; bdst = wb; sqdst = e2; row = wave - N_ROWS; }
    float4 v = *((const float4*)src + (size_t)row * (CDIM / 4) + lane);
    ushort4 o;
    o.x = f2bf_rne(v.x); o.y = f2bf_rne(v.y); o.z = f2bf_rne(v.z); o.w = f2bf_rne(v.w);
    *((ushort4*)bdst + (size_t)row * (CDIM / 4) + lane) = o;
    float s = v.x * v.x + v.y * v.y + v.z * v.z + v.w * v.w;
    for (int off = 32; off; off >>= 1) s += __shfl_down(s, off, 64);
    if (lane == 0) sqdst[row] = s;
}

// ---------- phase 1: 256x128 tile, 4 waves, BK=32 double-buffered, TRANSPOSED MFMA ----------
// 256 threads / 52.2 KB LDS -> 2 INDEPENDENT blocks per CU (round-2 lesson: a single
// barrier-synced block stalls the whole CU at each vmcnt drain; two blocks overlap).
// Operand swap: A = W codes, B = X rows  =>  D row (quad*4+reg) = code, D col (ln15) = x-row.
// A subtile's 16 codes then live in {4 regs x 4 quads}: per-subtile max = 3 v_max in-reg
// + 2 shfl_xor across quads (vs 4-step DPP chain per 2 rows) — ~2x cheaper epilogue, and
// the result is written with ONE unpredicated ds_write_u16 per lane per mi.
// LDS row = 32 bf16 (64B, 4x16B slots); slot p of row r holds global 16B chunk p ^ ((r>>1)&3)
// -> frag ds_read_b128 lands 2-way bank aliasing only (free, m136). Staged via pre-swizzled
// global source: lane l fetches chunk (l&3)^((l>>3)&3) (per-lane constant, 16-row calls).
__launch_bounds__(256, 2)
__global__ void vq_mfma_kernel(const ushort* __restrict__ xb, const ushort* __restrict__ wb,
                               __half* __restrict__ minT) {
    __shared__ ushort xs[2][256 * 32];   // 2 x 16 KB  (X: 256 rows x 32 cols)
    __shared__ ushort ws_l[2][128 * 32]; // 2 x 8 KB   (W: 128 codes x 32 cols)
    __shared__ ushort mbT[8][264];       // 4.125 KB transposed maxima (padded stride)

    const int t = threadIdx.x;
    const int w = t >> 6, lane = t & 63;
    const int ln15 = lane & 15, quad = lane >> 4;
    const int rt = blockIdx.x >> 6;     // 128 row tiles
    const int ct = blockIdx.x & 63;     // 64 code tiles
    const int rbase = (w >> 1) * 128;   // wave x-row base (0 or 128)
    const int cbase = (w & 1) * 64;     // wave code base (0 or 64)

    // staging geometry: per wave-call 16 rows x 32 cols (1KB); lane l -> row +(l>>2), slot l&3
    const int srow16 = lane >> 2;
    const int schunk = (lane & 3) ^ ((lane >> 3) & 3);   // pre-swizzled source 16B chunk
    const ushort* xsrc = xb + (size_t)(rt * 256 + w * 64 + srow16) * CDIM + schunk * 8;
    const ushort* wsrc = wb + (size_t)(ct * 128 + w * 32 + srow16) * CDIM + schunk * 8;

    f32x4 acc[4][8];                    // [ni: code blocks][mi: x-row blocks]
#pragma unroll
    for (int ni = 0; ni < 4; ++ni)
#pragma unroll
        for (int mi = 0; mi < 8; ++mi)
#pragma unroll
            for (int r = 0; r < 4; ++r) acc[ni][mi][r] = 0.f;

    // prologue: stage chunk 0 -> buf 0 (X: 4 calls/wave, W: 2 calls/wave)
#pragma unroll
    for (int j = 0; j < 4; ++j)
        GLOAD_LDS16(xsrc + (size_t)j * 16 * CDIM, &xs[0][(w * 64 + j * 16) * 32]);
#pragma unroll
    for (int j = 0; j < 2; ++j)
        GLOAD_LDS16(wsrc + (size_t)j * 16 * CDIM, &ws_l[0][(w * 32 + j * 16) * 32]);
    __syncthreads();

#pragma unroll
    for (int cc = 0; cc < 8; ++cc) {                  // 8 K-chunks of 32
        const int cur = cc & 1;
        if (cc < 7) {                                  // issue next-chunk loads FIRST
#pragma unroll
            for (int j = 0; j < 4; ++j)
                GLOAD_LDS16(xsrc + (size_t)j * 16 * CDIM + (cc + 1) * 32,
                            &xs[cur ^ 1][(w * 64 + j * 16) * 32]);
#pragma unroll
            for (int j = 0; j < 2; ++j)
                GLOAD_LDS16(wsrc + (size_t)j * 16 * CDIM + (cc + 1) * 32,
                            &ws_l[cur ^ 1][(w * 32 + j * 16) * 32]);
        }
        // frag reads: slot = quad ^ ((row>>1)&3); frag bases are mult. of 16 -> (ln15>>1)&3
        const int swz = (quad ^ ((ln15 >> 1) & 3)) * 8;
        bf16x8 a[4], b[8];
#pragma unroll
        for (int ni = 0; ni < 4; ++ni)
            a[ni] = *(const bf16x8*)&ws_l[cur][(cbase + ni * 16 + ln15) * 32 + swz];
#pragma unroll
        for (int mi = 0; mi < 8; ++mi)
            b[mi] = *(const bf16x8*)&xs[cur][(rbase + mi * 16 + ln15) * 32 + swz];
#pragma unroll
        for (int ni = 0; ni < 4; ++ni)
#pragma unroll
            for (int mi = 0; mi < 8; ++mi)
                acc[ni][mi] = __builtin_amdgcn_mfma_f32_16x16x32_bf16(a[ni], b[mi], acc[ni][mi], 0, 0, 0);
        __syncthreads();          // drains vmcnt -> buf^1 ready; protects buf reuse
    }

    // epilogue: codes are in {regs x quads}; 3 in-reg max + 2 cross-quad shfl per tile.
    // After reduction every lane holds mxn[ni] (max over subtile (cbase>>4)+ni for x-row
    // rbase+mi*16+ln15); lane (quad,ln15) stores ni=quad -> no predication.
#pragma unroll
    for (int mi = 0; mi < 8; ++mi) {
        float mxn[4];
#pragma unroll
        for (int ni = 0; ni < 4; ++ni) {
            f32x4 v = acc[ni][mi];
            float mx = fmaxf(fmaxf(v[0], v[1]), fmaxf(v[2], v[3]));
            mx = fmaxf(mx, __shfl_xor(mx, 16, 64));
            mx = fmaxf(mx, __shfl_xor(mx, 32, 64));
            mxn[ni] = mx;
        }
        float sel = quad == 0 ? mxn[0] : quad == 1 ? mxn[1] : quad == 2 ? mxn[2] : mxn[3];
        uint pk = __builtin_bit_cast(uint, __builtin_amdgcn_cvt_pkrtz(sel, sel));  // RTZ as certified
        mbT[(cbase >> 4) + quad][rbase + mi * 16 + ln15] = (ushort)(pk & 0xffffu);
    }
    __syncthreads();
    {
        // minT layout [rt][ct(64)][row(256)][sub(8)]: dense 4 KB per block (round-1 verified)
        union { ushort s[8]; uint4 u; } r;
#pragma unroll
        for (int s = 0; s < 8; ++s) r.s[s] = mbT[s][t];
        *(uint4*)(minT + ((size_t)(rt * 64 + ct) * 256 + t) * 8) = r.u;
    }
}

// ---------- phase 2: exact fp32 re-rank of candidate subtiles + fused gather ----------
// Latency-bound (VALUBusy 11%, Mfma 0): remedy is wave pool, not ILP tricks (round-2
// lesson: hand double-buffering regressed). (256,8) -> 32 waves/CU (was 16 at 50% occ);
// the block-wide __syncthreads is removed (each wave touches only its own LDS slice).
__launch_bounds__(256, 8)
__global__ void vq_rerank_kernel(const float* __restrict__ x, const float* __restrict__ wgt,
                                 const float* __restrict__ t1, const float* __restrict__ e2,
                                 const __half* __restrict__ minT,
                                 float* __restrict__ out_q, float* __restrict__ out_i) {
    __shared__ float xrow[4][256];
    __shared__ int slist[4][40];
    const int t = threadIdx.x, w = t >> 6, lane = t & 63, quad = lane >> 4;
    const int row = blockIdx.x * 4 + w;

    // stage x row (1 KB) into LDS
    *(float4*)&xrow[w][lane * 4] = *((const float4*)(x + (size_t)row * CDIM) + lane);

    // read 512 subtile dot-maxima (8 per lane): lane l covers ct-tile l (subtiles l*8..+7)
    union { uint4 u; __half2 h2[4]; } raw;
    raw.u = ((const uint4*)minT)[((size_t)(row >> 8) * 64 + lane) * 256 + (row & 255)];
    float m[8];
#pragma unroll
    for (int i = 0; i < 4; ++i) {
        float2 f = __half22float2(raw.h2[i]);
        m[2 * i] = f.x;
        m[2 * i + 1] = f.y;
    }
    float lmax = m[0];
#pragma unroll
    for (int i = 1; i < 8; ++i) lmax = fmaxf(lmax, m[i]);
#pragma unroll
    for (int off = 1; off < 64; off <<= 1) lmax = fmaxf(lmax, __shfl_xor(lmax, off, 64));
    const float thresh = lmax - MARGIN_DOT;

    // build candidate subtile list (certified superset of exact-min codes)
    int base = 0;
#pragma unroll
    for (int s = 0; s < 8; ++s) {
        bool c = (m[s] >= thresh);
        unsigned long long mask = __ballot(c);
        if (c) {
            int pos = base + __popcll(mask & ((1ull << lane) - 1ull));
            if (pos < 40) slist[w][pos] = lane * 8 + s;
        }
        base += (int)__popcll(mask);
    }
    const int ncand = base < 40 ? base : 40;
    // no __syncthreads: slist[w]/xrow[w] are wave-private; wave-internal LDS ordering
    // is handled by compiler-inserted lgkmcnt waits.

    const float t1r = t1[row];
    float best = 3.402823466e38f;
    int bestk = 0x7fffffff;
    for (int p = 0; p * 4 < ncand; ++p) {
        int li = p * 4 + quad;                 // 4 subtiles per pass, 16 lanes each
        float d = 3.402823466e38f;
        int k = 0x7fffffff;
        if (li < ncand) {
            int st = slist[w][li];
            k = st * 16 + (lane & 15);
            // EXACT accumulation order: sequential c = 0..255, fmaf chain (verified).
            float acc = 0.f;
            const float4* wp = (const float4*)(wgt + (size_t)k * CDIM);
#pragma unroll
            for (int c4 = 0; c4 < 64; ++c4) {
                float4 wv = wp[c4];
                float4 xv = *(const float4*)&xrow[w][c4 * 4];
                acc = fmaf(xv.x, wv.x, acc);
                acc = fmaf(xv.y, wv.y, acc);
                acc = fmaf(xv.z, wv.z, acc);
                acc = fmaf(xv.w, wv.w, acc);
            }
            d = (t1r + e2[k]) - 2.0f * acc;    // exact distance, same chain as before
        }
        if (d < best || (d == best && k < bestk)) { best = d; bestk = k; }
    }
    // wave-reduce (d, k) with first-index tie-break (np argmin semantics)
#pragma unroll
    for (int off = 1; off < 64; off <<= 1) {
        float od = __shfl_xor(best, off, 64);
        int ok = __shfl_xor(bestk, off, 64);
        if (od < best || (od == best && ok < bestk)) { best = od; bestk = ok; }
    }

    // fused gather + index write
    const float4* src = (const float4*)(wgt + (size_t)bestk * CDIM);
    ((float4*)(out_q + (size_t)row * CDIM))[lane] = src[lane];
    if (lane == 0) out_i[row] = (float)bestk;
}

extern "C" void kernel_launch(void* const* d_in, const int* in_sizes, int n_in,
                              void* d_out, int out_size, void* d_ws, size_t ws_size,
                              hipStream_t stream) {
    const float* x = (const float*)d_in[0];   // (8,4096,256) fp32
    const float* wgt = (const float*)d_in[1]; // (8192,256) fp32

    float* out_q = (float*)d_out;
    float* out_i = out_q + (size_t)N_ROWS * CDIM;

    // workspace carve (all 16B aligned): e2, t1, minT, xb, wb  -> ~52.3 MB
    char* p = (char*)d_ws;
    float* e2 = (float*)p;               p += (size_t)KCODES * 4;
    float* t1 = (float*)p;               p += (size_t)N_ROWS * 4;
    __half* minT = (__half*)p;           p += (size_t)N_ROWS * NSUB * 2;
    ushort* xb = (ushort*)p;             p += (size_t)N_ROWS * CDIM * 2;
    ushort* wb = (ushort*)p;             p += (size_t)KCODES * CDIM * 2;

    prep_kernel<<<(N_ROWS + KCODES) / 4, 256, 0, stream>>>(x, wgt, xb, wb, t1, e2);

    vq_mfma_kernel<<<(N_ROWS / 256) * (KCODES / 128), 256, 0, stream>>>(xb, wb, minT);
    vq_rerank_kernel<<<N_ROWS / 4, 256, 0, stream>>>(x, wgt, t1, e2, minT, out_q, out_i);
}

// Round 4
// 414.094 us; speedup vs baseline: 1.1608x; 1.0124x over previous
//
#include <hip/hip_runtime.h>
#include <hip/hip_fp16.h>

#define N_ROWS 32768
#define KCODES 8192
#define CDIM   256
#define NSUB   (KCODES / 16)     // 512 subtiles of 16 codes
// dot-scale margin: covers bf16-dot err + fp16-RTZ storage (~3e-5) + e2 spread (<=1.9e-6).
// Certified need ~1.05e-4; rounds 2-3 passed with this exact value + raw-dot-max semantics.
#define MARGIN_DOT 2.2e-4f
#define RPB    16                // rerank rows per block
#define MAXE   256               // worklist cap (expected E ~ 20; prev cap was 40/row)

typedef __attribute__((ext_vector_type(8))) short bf16x8;
typedef __attribute__((ext_vector_type(4))) float f32x4;

// async global->LDS, 16B per lane; LDS dest is wave-uniform base + lane*16 (linear),
// so the XOR swizzle is applied to the per-lane GLOBAL source address instead (rule #21).
#define GLOAD_LDS16(g, l)                                                              \
    __builtin_amdgcn_global_load_lds((const __attribute__((address_space(1))) void*)(g), \
                                     (__attribute__((address_space(3))) void*)(l), 16, 0, 0)

__device__ __forceinline__ ushort f2bf_rne(float f) {
    unsigned u = __float_as_uint(f);
    u += 0x7fffu + ((u >> 16) & 1u);
    return (ushort)(u >> 16);
}

// ---------- phase 0: fused fp32->bf16 convert + row sum-of-squares for BOTH inputs ----------
__global__ void prep_kernel(const float* __restrict__ x, const float* __restrict__ wgt,
                            ushort* __restrict__ xb, ushort* __restrict__ wb,
                            float* __restrict__ t1, float* __restrict__ e2) {
    int wave = (blockIdx.x * blockDim.x + threadIdx.x) >> 6;
    int lane = threadIdx.x & 63;
    const float* src; ushort* bdst; float* sqdst; int row;
    if (wave < N_ROWS) { src = x; bdst = xb; sqdst = t1; row = wave; }
    else               { src = wgt; bdst = wb; sqdst = e2; row = wave - N_ROWS; }
    float4 v = *((const float4*)src + (size_t)row * (CDIM / 4) + lane);
    ushort4 o;
    o.x = f2bf_rne(v.x); o.y = f2bf_rne(v.y); o.z = f2bf_rne(v.z); o.w = f2bf_rne(v.w);
    *((ushort4*)bdst + (size_t)row * (CDIM / 4) + lane) = o;
    float s = v.x * v.x + v.y * v.y + v.z * v.z + v.w * v.w;
    for (int off = 32; off; off >>= 1) s += __shfl_down(s, off, 64);
    if (lane == 0) sqdst[row] = s;
}

// ---------- phase 1: 256x128 tile, 4 waves, BK=32 double-buffered, TRANSPOSED MFMA ----------
// (unchanged from round 3 — counters should surface next round once rerank stops dominating)
__launch_bounds__(256, 2)
__global__ void vq_mfma_kernel(const ushort* __restrict__ xb, const ushort* __restrict__ wb,
                               __half* __restrict__ minT) {
    __shared__ ushort xs[2][256 * 32];   // 2 x 16 KB  (X: 256 rows x 32 cols)
    __shared__ ushort ws_l[2][128 * 32]; // 2 x 8 KB   (W: 128 codes x 32 cols)
    __shared__ ushort mbT[8][264];       // 4.125 KB transposed maxima (padded stride)

    const int t = threadIdx.x;
    const int w = t >> 6, lane = t & 63;
    const int ln15 = lane & 15, quad = lane >> 4;
    const int rt = blockIdx.x >> 6;     // 128 row tiles
    const int ct = blockIdx.x & 63;     // 64 code tiles
    const int rbase = (w >> 1) * 128;   // wave x-row base (0 or 128)
    const int cbase = (w & 1) * 64;     // wave code base (0 or 64)

    // staging geometry: per wave-call 16 rows x 32 cols (1KB); lane l -> row +(l>>2), slot l&3
    const int srow16 = lane >> 2;
    const int schunk = (lane & 3) ^ ((lane >> 3) & 3);   // pre-swizzled source 16B chunk
    const ushort* xsrc = xb + (size_t)(rt * 256 + w * 64 + srow16) * CDIM + schunk * 8;
    const ushort* wsrc = wb + (size_t)(ct * 128 + w * 32 + srow16) * CDIM + schunk * 8;

    f32x4 acc[4][8];                    // [ni: code blocks][mi: x-row blocks]
#pragma unroll
    for (int ni = 0; ni < 4; ++ni)
#pragma unroll
        for (int mi = 0; mi < 8; ++mi)
#pragma unroll
            for (int r = 0; r < 4; ++r) acc[ni][mi][r] = 0.f;

    // prologue: stage chunk 0 -> buf 0 (X: 4 calls/wave, W: 2 calls/wave)
#pragma unroll
    for (int j = 0; j < 4; ++j)
        GLOAD_LDS16(xsrc + (size_t)j * 16 * CDIM, &xs[0][(w * 64 + j * 16) * 32]);
#pragma unroll
    for (int j = 0; j < 2; ++j)
        GLOAD_LDS16(wsrc + (size_t)j * 16 * CDIM, &ws_l[0][(w * 32 + j * 16) * 32]);
    __syncthreads();

#pragma unroll
    for (int cc = 0; cc < 8; ++cc) {                  // 8 K-chunks of 32
        const int cur = cc & 1;
        if (cc < 7) {                                  // issue next-chunk loads FIRST
#pragma unroll
            for (int j = 0; j < 4; ++j)
                GLOAD_LDS16(xsrc + (size_t)j * 16 * CDIM + (cc + 1) * 32,
                            &xs[cur ^ 1][(w * 64 + j * 16) * 32]);
#pragma unroll
            for (int j = 0; j < 2; ++j)
                GLOAD_LDS16(wsrc + (size_t)j * 16 * CDIM + (cc + 1) * 32,
                            &ws_l[cur ^ 1][(w * 32 + j * 16) * 32]);
        }
        // frag reads: slot = quad ^ ((row>>1)&3); frag bases are mult. of 16 -> (ln15>>1)&3
        const int swz = (quad ^ ((ln15 >> 1) & 3)) * 8;
        bf16x8 a[4], b[8];
#pragma unroll
        for (int ni = 0; ni < 4; ++ni)
            a[ni] = *(const bf16x8*)&ws_l[cur][(cbase + ni * 16 + ln15) * 32 + swz];
#pragma unroll
        for (int mi = 0; mi < 8; ++mi)
            b[mi] = *(const bf16x8*)&xs[cur][(rbase + mi * 16 + ln15) * 32 + swz];
#pragma unroll
        for (int ni = 0; ni < 4; ++ni)
#pragma unroll
            for (int mi = 0; mi < 8; ++mi)
                acc[ni][mi] = __builtin_amdgcn_mfma_f32_16x16x32_bf16(a[ni], b[mi], acc[ni][mi], 0, 0, 0);
        __syncthreads();          // drains vmcnt -> buf^1 ready; protects buf reuse
    }

    // epilogue: codes live in {regs x quads}; 3 in-reg max + 2 cross-quad shfl per tile.
#pragma unroll
    for (int mi = 0; mi < 8; ++mi) {
        float mxn[4];
#pragma unroll
        for (int ni = 0; ni < 4; ++ni) {
            f32x4 v = acc[ni][mi];
            float mx = fmaxf(fmaxf(v[0], v[1]), fmaxf(v[2], v[3]));
            mx = fmaxf(mx, __shfl_xor(mx, 16, 64));
            mx = fmaxf(mx, __shfl_xor(mx, 32, 64));
            mxn[ni] = mx;
        }
        float sel = quad == 0 ? mxn[0] : quad == 1 ? mxn[1] : quad == 2 ? mxn[2] : mxn[3];
        uint pk = __builtin_bit_cast(uint, __builtin_amdgcn_cvt_pkrtz(sel, sel));  // RTZ as certified
        mbT[(cbase >> 4) + quad][rbase + mi * 16 + ln15] = (ushort)(pk & 0xffffu);
    }
    __syncthreads();
    {
        // minT layout [rt][ct(64)][row(256)][sub(8)]: dense 4 KB per block
        union { ushort s[8]; uint4 u; } r;
#pragma unroll
        for (int s = 0; s < 8; ++s) r.s[s] = mbT[s][t];
        *(uint4*)(minT + ((size_t)(rt * 64 + ct) * 256 + t) * 8) = r.u;
    }
}

// ---------- phase 2: pooled-worklist exact fp32 re-rank + fused gather ----------
// Round-3 diagnosis: ncand ~ 1 subtile/row -> old scheme lit 16/64 lanes and ran
// ~16 serially-dependent fmaf chains per CU (VALUBusy 12%, 2.2 TB/s latency-bound).
// New: block = 16 rows; per-row scan (identical math) appends (row,subtile) entries
// to a block worklist; all 256 threads then process entries at 16 lanes/entry.
// Per-code chain, d formula, candidate set, and (d,k) tie-break are BIT-IDENTICAL;
// only the schedule changed. key=(bits(d)<<32)|k: d>0 always (d ~ t1 ~ 256), so
// uint64 min == (min d, then min k) exactly.
__launch_bounds__(256, 8)
__global__ void vq_rerank_kernel(const float* __restrict__ x, const float* __restrict__ wgt,
                                 const float* __restrict__ t1, const float* __restrict__ e2,
                                 const __half* __restrict__ minT,
                                 float* __restrict__ out_q, float* __restrict__ out_i) {
    __shared__ float xrow[RPB][256];                  // 16 KB exact fp32 x rows
    __shared__ int wl[MAXE];                          // (row<<9)|subtile
    __shared__ unsigned long long res[MAXE];          // per-entry reduced key
    __shared__ int bestk_s[RPB];
    __shared__ int nwl;

    const int t = threadIdx.x, w = t >> 6, lane = t & 63;
    const int g = t >> 4, gl = t & 15;                // 16 groups x 16 lanes
    const int row0 = blockIdx.x * RPB;

    if (t == 0) nwl = 0;

    // stage 16 exact fp32 x rows (64 KB global -> 16 KB? no: 16 rows x 1 KB = 16 KB)
    {
        const float4* xsrc = (const float4*)(x + (size_t)(row0 + g) * CDIM);
        float4* xd = (float4*)&xrow[g][0];
#pragma unroll
        for (int j = 0; j < 4; ++j) xd[gl + 16 * j] = xsrc[gl + 16 * j];
    }
    __syncthreads();                                  // nwl init visible; xrow in flight

    // scan: wave w handles rows 4w..4w+3; per row identical threshold math as rounds 1-3
    for (int i = 0; i < 4; ++i) {
        const int rr = w * 4 + i;                     // local row
        const int rowg = row0 + rr;
        union { uint4 u; __half2 h2[4]; } raw;
        raw.u = ((const uint4*)minT)[((size_t)(rowg >> 8) * 64 + lane) * 256 + (rowg & 255)];
        float m[8];
#pragma unroll
        for (int q = 0; q < 4; ++q) {
            float2 f = __half22float2(raw.h2[q]);
            m[2 * q] = f.x;
            m[2 * q + 1] = f.y;
        }
        float lmax = m[0];
#pragma unroll
        for (int q = 1; q < 8; ++q) lmax = fmaxf(lmax, m[q]);
#pragma unroll
        for (int off = 1; off < 64; off <<= 1) lmax = fmaxf(lmax, __shfl_xor(lmax, off, 64));
        const float thresh = lmax - MARGIN_DOT;
#pragma unroll
        for (int s = 0; s < 8; ++s) {
            bool c = (m[s] >= thresh);
            unsigned long long mask = __ballot(c);
            int cnt = (int)__popcll(mask);
            int basepos = 0;
            if (lane == 0 && cnt) basepos = atomicAdd(&nwl, cnt);
            basepos = __shfl(basepos, 0, 64);
            if (c) {
                int pos = basepos + (int)__popcll(mask & ((1ull << lane) - 1ull));
                if (pos < MAXE) wl[pos] = (rr << 9) | (lane * 8 + s);
            }
        }
    }
    __syncthreads();

    const int E = nwl < MAXE ? nwl : MAXE;
    // process entries: 16 groups in parallel, 16 lanes per entry (one code each)
    for (int e0 = 0; e0 < E; e0 += 16) {
        const int e = e0 + g;
        unsigned long long key = ~0ull;
        if (e < E) {
            const int ent = wl[e];
            const int rr = ent >> 9, st = ent & 511;
            const int k = st * 16 + gl;
            // EXACT accumulation order: sequential c = 0..255, fmaf chain (unchanged).
            float acc = 0.f;
            const float4* wp = (const float4*)(wgt + (size_t)k * CDIM);
#pragma unroll
            for (int c4 = 0; c4 < 64; ++c4) {
                float4 wv = wp[c4];
                float4 xv = *(const float4*)&xrow[rr][c4 * 4];
                acc = fmaf(xv.x, wv.x, acc);
                acc = fmaf(xv.y, wv.y, acc);
                acc = fmaf(xv.z, wv.z, acc);
                acc = fmaf(xv.w, wv.w, acc);
            }
            float d = (t1[row0 + rr] + e2[k]) - 2.0f * acc;   // exact, same chain
            key = ((unsigned long long)__float_as_uint(d) << 32) | (uint)k;
        }
        // min over the entry's 16 codes (xor<16 stays within the 16-lane group)
#pragma unroll
        for (int off = 1; off < 16; off <<= 1) {
            unsigned long long ok = __shfl_xor(key, off, 64);
            key = ok < key ? ok : key;
        }
        if (gl == 0 && e < E) res[e] = key;
    }
    __syncthreads();

    // per-row final min over its entries (E ~ 20: trivial serial scan by 16 threads)
    if (t < RPB) {
        unsigned long long best = ~0ull;
        for (int e = 0; e < E; ++e)
            if ((wl[e] >> 9) == t) {
                unsigned long long v = res[e];
                best = v < best ? v : best;
            }
        const int bk = (int)(uint)(best & 0xffffffffu);
        bestk_s[t] = bk;
        out_i[row0 + t] = (float)bk;
    }
    __syncthreads();

    // fused gather: group g copies row g's winning code row (4 x 256B coalesced runs)
    {
        const float4* src = (const float4*)(wgt + (size_t)bestk_s[g] * CDIM);
        float4* dst = (float4*)(out_q + (size_t)(row0 + g) * CDIM);
#pragma unroll
        for (int j = 0; j < 4; ++j) dst[gl + 16 * j] = src[gl + 16 * j];
    }
}

extern "C" void kernel_launch(void* const* d_in, const int* in_sizes, int n_in,
                              void* d_out, int out_size, void* d_ws, size_t ws_size,
                              hipStream_t stream) {
    const float* x = (const float*)d_in[0];   // (8,4096,256) fp32
    const float* wgt = (const float*)d_in[1]; // (8192,256) fp32

    float* out_q = (float*)d_out;
    float* out_i = out_q + (size_t)N_ROWS * CDIM;

    // workspace carve (all 16B aligned): e2, t1, minT, xb, wb  -> ~52.3 MB
    char* p = (char*)d_ws;
    float* e2 = (float*)p;               p += (size_t)KCODES * 4;
    float* t1 = (float*)p;               p += (size_t)N_ROWS * 4;
    __half* minT = (__half*)p;           p += (size_t)N_ROWS * NSUB * 2;
    ushort* xb = (ushort*)p;             p += (size_t)N_ROWS * CDIM * 2;
    ushort* wb = (ushort*)p;             p += (size_t)KCODES * CDIM * 2;

    prep_kernel<<<(N_ROWS + KCODES) / 4, 256, 0, stream>>>(x, wgt, xb, wb, t1, e2);

    vq_mfma_kernel<<<(N_ROWS / 256) * (KCODES / 128), 256, 0, stream>>>(xb, wb, minT);
    vq_rerank_kernel<<<N_ROWS / RPB, 256, 0, stream>>>(x, wgt, t1, e2, minT, out_q, out_i);
}

// Round 6
// 407.878 us; speedup vs baseline: 1.1785x; 1.0152x over previous
//
#include <hip/hip_runtime.h>
#include <hip/hip_fp16.h>

#define N_ROWS 32768
#define KCODES 8192
#define CDIM   256
#define NSUB   (KCODES / 16)     // 512 subtiles of 16 codes
// dot-scale margin: covers bf16-dot err + fp16-RTZ storage (~3e-5) + e2 spread (<=1.9e-6).
// Certified need ~1.05e-4; rounds 2-4 passed with this exact value + raw-dot-max semantics.
#define MARGIN_DOT 2.2e-4f
#define RPB    16                // rerank rows per block
#define MAXE   256               // worklist cap (E ~ 20 expected; E >= 16 guaranteed)

typedef __attribute__((ext_vector_type(8))) short bf16x8;
typedef __attribute__((ext_vector_type(4))) float f32x4;

// async global->LDS, 16B per lane; LDS dest is wave-uniform base + lane*16 (linear),
// so XOR swizzles are applied to the per-lane GLOBAL source address instead (rule #21).
#define GLOAD_LDS16(g, l)                                                              \
    __builtin_amdgcn_global_load_lds((const __attribute__((address_space(1))) void*)(g), \
                                     (__attribute__((address_space(3))) void*)(l), 16, 0, 0)

__device__ __forceinline__ ushort f2bf_rne(float f) {
    unsigned u = __float_as_uint(f);
    u += 0x7fffu + ((u >> 16) & 1u);
    return (ushort)(u >> 16);
}

// ---------- phase 0: fused fp32->bf16 convert + row sum-of-squares for BOTH inputs ----------
__global__ void prep_kernel(const float* __restrict__ x, const float* __restrict__ wgt,
                            ushort* __restrict__ xb, ushort* __restrict__ wb,
                            float* __restrict__ t1, float* __restrict__ e2) {
    int wave = (blockIdx.x * blockDim.x + threadIdx.x) >> 6;
    int lane = threadIdx.x & 63;
    const float* src; ushort* bdst; float* sqdst; int row;
    if (wave < N_ROWS) { src = x; bdst = xb; sqdst = t1; row = wave; }
    else               { src = wgt; bdst = wb; sqdst = e2; row = wave - N_ROWS; }
    float4 v = *((const float4*)src + (size_t)row * (CDIM / 4) + lane);
    ushort4 o;
    o.x = f2bf_rne(v.x); o.y = f2bf_rne(v.y); o.z = f2bf_rne(v.z); o.w = f2bf_rne(v.w);
    *((ushort4*)bdst + (size_t)row * (CDIM / 4) + lane) = o;
    float s = v.x * v.x + v.y * v.y + v.z * v.z + v.w * v.w;
    for (int off = 32; off; off >>= 1) s += __shfl_down(s, off, 64);
    if (lane == 0) sqdst[row] = s;
}

// ---------- phase 1: 256x128 tile, 8 waves x (64x64), BK=32 dbuf, TRANSPOSED MFMA ----------
// Round-5 occupancy analysis: the 4-wave 128x64-tile version needs acc[4][8]=128 VGPR
// + 12 live frags ~= 190 VGPR -> 512/190 = 2 waves/SIMD; ds_read_b128 (~12cy x 12/chunk)
// can't hide under MFMA with one partner wave -> MfmaUtil ~31%. This version: 8 waves,
// wave tile 64x64 -> acc[4][4]=64 VGPR, ~125 total -> 4 waves/SIMD, still 2 independent
// blocks/CU (LDS 53.4 KB). Fragment/swizzle/epilogue algebra IDENTICAL to the verified
// rounds-3/4 kernel; only wave-tile geometry (rbase/cbase/mi-range/staging counts) changed.
__launch_bounds__(512, 3)
__global__ void vq_mfma_kernel(const ushort* __restrict__ xb, const ushort* __restrict__ wb,
                               __half* __restrict__ minT) {
    __shared__ ushort xs[2][256 * 32];   // 2 x 16 KB  (X: 256 rows x 32 cols)
    __shared__ ushort ws_l[2][128 * 32]; // 2 x 8 KB   (W: 128 codes x 32 cols)
    __shared__ ushort mbT[8][264];       // 4.125 KB transposed maxima (padded stride)

    const int t = threadIdx.x;
    const int w = t >> 6, lane = t & 63;
    const int ln15 = lane & 15, quad = lane >> 4;
    const int rt = blockIdx.x >> 6;     // 128 row tiles
    const int ct = blockIdx.x & 63;     // 64 code tiles
    const int rbase = (w >> 1) * 64;    // wave x-row base (0/64/128/192)
    const int cbase = (w & 1) * 64;     // wave code base (0 or 64)

    // staging geometry: per wave-call 16 rows x 32 cols (1KB); lane l -> row +(l>>2), slot l&3
    // LDS (row r, pos p) holds global chunk p ^ ((r>>1)&3); row bases are multiples of 16,
    // so source swizzle (l&3)^((l>>3)&3) is identical to the verified rounds-3/4 mapping.
    const int srow16 = lane >> 2;
    const int schunk = (lane & 3) ^ ((lane >> 3) & 3);   // pre-swizzled source 16B chunk
    const ushort* xsrc = xb + (size_t)(rt * 256 + w * 32 + srow16) * CDIM + schunk * 8;
    const ushort* wsrc = wb + (size_t)(ct * 128 + w * 16 + srow16) * CDIM + schunk * 8;

    f32x4 acc[4][4];                    // [ni: code blocks][mi: x-row blocks]
#pragma unroll
    for (int ni = 0; ni < 4; ++ni)
#pragma unroll
        for (int mi = 0; mi < 4; ++mi)
#pragma unroll
            for (int r = 0; r < 4; ++r) acc[ni][mi][r] = 0.f;

    // prologue: stage chunk 0 -> buf 0 (X: 2 calls/wave, W: 1 call/wave)
#pragma unroll
    for (int j = 0; j < 2; ++j)
        GLOAD_LDS16(xsrc + (size_t)j * 16 * CDIM, &xs[0][(w * 32 + j * 16) * 32]);
    GLOAD_LDS16(wsrc, &ws_l[0][(w * 16) * 32]);
    __syncthreads();

#pragma unroll
    for (int cc = 0; cc < 8; ++cc) {                  // 8 K-chunks of 32
        const int cur = cc & 1;
        if (cc < 7) {                                  // issue next-chunk loads FIRST
#pragma unroll
            for (int j = 0; j < 2; ++j)
                GLOAD_LDS16(xsrc + (size_t)j * 16 * CDIM + (cc + 1) * 32,
                            &xs[cur ^ 1][(w * 32 + j * 16) * 32]);
            GLOAD_LDS16(wsrc + (cc + 1) * 32, &ws_l[cur ^ 1][(w * 16) * 32]);
        }
        // frag reads: unswizzled K-segment = quad*8; XOR undoes the (row>>1)&3 store swizzle
        const int swz = (quad ^ ((ln15 >> 1) & 3)) * 8;
        bf16x8 a[4], b[4];
#pragma unroll
        for (int ni = 0; ni < 4; ++ni)
            a[ni] = *(const bf16x8*)&ws_l[cur][(cbase + ni * 16 + ln15) * 32 + swz];
#pragma unroll
        for (int mi = 0; mi < 4; ++mi)
            b[mi] = *(const bf16x8*)&xs[cur][(rbase + mi * 16 + ln15) * 32 + swz];
#pragma unroll
        for (int ni = 0; ni < 4; ++ni)
#pragma unroll
            for (int mi = 0; mi < 4; ++mi)
                acc[ni][mi] = __builtin_amdgcn_mfma_f32_16x16x32_bf16(a[ni], b[mi], acc[ni][mi], 0, 0, 0);
        __syncthreads();          // drains vmcnt -> buf^1 ready; protects buf reuse
    }

    // epilogue (verified in rounds 3-4): codes live in {regs x quads};
    // 3 in-reg max + 2 cross-quad shfl per tile; lane (quad,ln15) stores ni=quad.
#pragma unroll
    for (int mi = 0; mi < 4; ++mi) {
        float mxn[4];
#pragma unroll
        for (int ni = 0; ni < 4; ++ni) {
            f32x4 v = acc[ni][mi];
            float mx = fmaxf(fmaxf(v[0], v[1]), fmaxf(v[2], v[3]));
            mx = fmaxf(mx, __shfl_xor(mx, 16, 64));
            mx = fmaxf(mx, __shfl_xor(mx, 32, 64));
            mxn[ni] = mx;
        }
        float sel = quad == 0 ? mxn[0] : quad == 1 ? mxn[1] : quad == 2 ? mxn[2] : mxn[3];
        uint pk = __builtin_bit_cast(uint, __builtin_amdgcn_cvt_pkrtz(sel, sel));  // RTZ as certified
        mbT[(cbase >> 4) + quad][rbase + mi * 16 + ln15] = (ushort)(pk & 0xffffu);
    }
    __syncthreads();
    if (t < 256) {
        // minT layout [rt][ct(64)][row(256)][sub(8)]: dense 4 KB per block
        union { ushort s[8]; uint4 u; } r;
#pragma unroll
        for (int s = 0; s < 8; ++s) r.s[s] = mbT[s][t];
        *(uint4*)(minT + ((size_t)(rt * 64 + ct) * 256 + t) * 8) = r.u;
    }
}

// ---------- phase 2: pooled-worklist exact fp32 re-rank + fused gather ----------
// VERBATIM restore of the round-4 version (passed, 195.6 us). Round-5's DMA staging of
// wgt corrupted the dots (indices-only failure: with U(-1/K,1/K) weights, quantized
// output passes regardless of selection -- indices are the real argmin check).
__launch_bounds__(256, 8)
__global__ void vq_rerank_kernel(const float* __restrict__ x, const float* __restrict__ wgt,
                                 const float* __restrict__ t1, const float* __restrict__ e2,
                                 const __half* __restrict__ minT,
                                 float* __restrict__ out_q, float* __restrict__ out_i) {
    __shared__ float xrow[RPB][256];                  // 16 KB exact fp32 x rows
    __shared__ int wl[MAXE];                          // (row<<9)|subtile
    __shared__ unsigned long long res[MAXE];          // per-entry reduced key
    __shared__ int bestk_s[RPB];
    __shared__ int nwl;

    const int t = threadIdx.x, w = t >> 6, lane = t & 63;
    const int g = t >> 4, gl = t & 15;                // 16 groups x 16 lanes
    const int row0 = blockIdx.x * RPB;

    if (t == 0) nwl = 0;

    // stage 16 exact fp32 x rows (16 rows x 1 KB = 16 KB)
    {
        const float4* xsrc = (const float4*)(x + (size_t)(row0 + g) * CDIM);
        float4* xd = (float4*)&xrow[g][0];
#pragma unroll
        for (int j = 0; j < 4; ++j) xd[gl + 16 * j] = xsrc[gl + 16 * j];
    }
    __syncthreads();                                  // nwl init visible; xrow in flight

    // scan: wave w handles rows 4w..4w+3; per row identical threshold math as rounds 1-4
    for (int i = 0; i < 4; ++i) {
        const int rr = w * 4 + i;                     // local row
        const int rowg = row0 + rr;
        union { uint4 u; __half2 h2[4]; } raw;
        raw.u = ((const uint4*)minT)[((size_t)(rowg >> 8) * 64 + lane) * 256 + (rowg & 255)];
        float m[8];
#pragma unroll
        for (int q = 0; q < 4; ++q) {
            float2 f = __half22float2(raw.h2[q]);
            m[2 * q] = f.x;
            m[2 * q + 1] = f.y;
        }
        float lmax = m[0];
#pragma unroll
        for (int q = 1; q < 8; ++q) lmax = fmaxf(lmax, m[q]);
#pragma unroll
        for (int off = 1; off < 64; off <<= 1) lmax = fmaxf(lmax, __shfl_xor(lmax, off, 64));
        const float thresh = lmax - MARGIN_DOT;
#pragma unroll
        for (int s = 0; s < 8; ++s) {
            bool c = (m[s] >= thresh);
            unsigned long long mask = __ballot(c);
            int cnt = (int)__popcll(mask);
            int basepos = 0;
            if (lane == 0 && cnt) basepos = atomicAdd(&nwl, cnt);
            basepos = __shfl(basepos, 0, 64);
            if (c) {
                int pos = basepos + (int)__popcll(mask & ((1ull << lane) - 1ull));
                if (pos < MAXE) wl[pos] = (rr << 9) | (lane * 8 + s);
            }
        }
    }
    __syncthreads();

    const int E = nwl < MAXE ? nwl : MAXE;
    // process entries: 16 groups in parallel, 16 lanes per entry (one code each)
    for (int e0 = 0; e0 < E; e0 += 16) {
        const int e = e0 + g;
        unsigned long long key = ~0ull;
        if (e < E) {
            const int ent = wl[e];
            const int rr = ent >> 9, st = ent & 511;
            const int k = st * 16 + gl;
            // EXACT accumulation order: sequential c = 0..255, fmaf chain (unchanged).
            float acc = 0.f;
            const float4* wp = (const float4*)(wgt + (size_t)k * CDIM);
#pragma unroll
            for (int c4 = 0; c4 < 64; ++c4) {
                float4 wv = wp[c4];
                float4 xv = *(const float4*)&xrow[rr][c4 * 4];
                acc = fmaf(xv.x, wv.x, acc);
                acc = fmaf(xv.y, wv.y, acc);
                acc = fmaf(xv.z, wv.z, acc);
                acc = fmaf(xv.w, wv.w, acc);
            }
            float d = (t1[row0 + rr] + e2[k]) - 2.0f * acc;   // exact, same chain
            key = ((unsigned long long)__float_as_uint(d) << 32) | (uint)k;
        }
        // min over the entry's 16 codes (xor<16 stays within the 16-lane group)
#pragma unroll
        for (int off = 1; off < 16; off <<= 1) {
            unsigned long long ok = __shfl_xor(key, off, 64);
            key = ok < key ? ok : key;
        }
        if (gl == 0 && e < E) res[e] = key;
    }
    __syncthreads();

    // per-row final min over its entries (E ~ 20: trivial serial scan by 16 threads)
    if (t < RPB) {
        unsigned long long best = ~0ull;
        for (int e = 0; e < E; ++e)
            if ((wl[e] >> 9) == t) {
                unsigned long long v = res[e];
                best = v < best ? v : best;
            }
        const int bk = (int)(uint)(best & 0xffffffffu);
        bestk_s[t] = bk;
        out_i[row0 + t] = (float)bk;
    }
    __syncthreads();

    // fused gather: group g copies row g's winning code row (4 x 256B coalesced runs)
    {
        const float4* src = (const float4*)(wgt + (size_t)bestk_s[g] * CDIM);
        float4* dst = (float4*)(out_q + (size_t)(row0 + g) * CDIM);
#pragma unroll
        for (int j = 0; j < 4; ++j) dst[gl + 16 * j] = src[gl + 16 * j];
    }
}

extern "C" void kernel_launch(void* const* d_in, const int* in_sizes, int n_in,
                              void* d_out, int out_size, void* d_ws, size_t ws_size,
                              hipStream_t stream) {
    const float* x = (const float*)d_in[0];   // (8,4096,256) fp32
    const float* wgt = (const float*)d_in[1]; // (8192,256) fp32

    float* out_q = (float*)d_out;
    float* out_i = out_q + (size_t)N_ROWS * CDIM;

    // workspace carve (all 16B aligned): e2, t1, minT, xb, wb  -> ~52.3 MB
    char* p = (char*)d_ws;
    float* e2 = (float*)p;               p += (size_t)KCODES * 4;
    float* t1 = (float*)p;               p += (size_t)N_ROWS * 4;
    __half* minT = (__half*)p;           p += (size_t)N_ROWS * NSUB * 2;
    ushort* xb = (ushort*)p;             p += (size_t)N_ROWS * CDIM * 2;
    ushort* wb = (ushort*)p;             p += (size_t)KCODES * CDIM * 2;

    prep_kernel<<<(N_ROWS + KCODES) / 4, 256, 0, stream>>>(x, wgt, xb, wb, t1, e2);

    vq_mfma_kernel<<<(N_ROWS / 256) * (KCODES / 128), 512, 0, stream>>>(xb, wb, minT);
    vq_rerank_kernel<<<N_ROWS / RPB, 256, 0, stream>>>(x, wgt, t1, e2, minT, out_q, out_i);
}